// Round 7
// baseline (115.332 us; speedup 1.0000x reference)
//
#include <hip/hip_runtime.h>
#include <math.h>

#define NT 32768
#define SCALEF 4.0f

typedef _Float16 h2v __attribute__((ext_vector_type(2)));

// broadcast-readlane (uint)
__device__ __forceinline__ unsigned rlu(unsigned u, int l) {
    return (unsigned)__builtin_amdgcn_readlane((int)u, l);
}

// pack two fp32 into f16x2 (RNE)
__device__ __forceinline__ unsigned pk2(float lo, float hi) {
    unsigned a = (unsigned)__builtin_bit_cast(unsigned short, (_Float16)lo);
    unsigned b = (unsigned)__builtin_bit_cast(unsigned short, (_Float16)hi);
    return a | (b << 16);
}
__device__ __forceinline__ float upk_lo(unsigned u) {
    return (float)__builtin_bit_cast(_Float16, (unsigned short)(u & 0xffffu));
}

// 2 MACs: acc += w.f16x2 . h.f16x2 (v_dot2_f32_f16, fp32 accumulate)
__device__ __forceinline__ float dot2(unsigned w, unsigned h, float acc) {
#if defined(__has_builtin) && __has_builtin(__builtin_amdgcn_fdot2)
    return __builtin_amdgcn_fdot2(__builtin_bit_cast(h2v, w),
                                  __builtin_bit_cast(h2v, h), acc, false);
#else
    float r = fmaf(upk_lo(w), upk_lo(h), acc);
    return fmaf((float)__builtin_bit_cast(_Float16, (unsigned short)(w >> 16)),
                (float)__builtin_bit_cast(_Float16, (unsigned short)(h >> 16)), r);
#endif
}

__device__ __forceinline__ float sigf(float x) {
    return __builtin_amdgcn_rcpf(1.0f + __expf(-x));
}
__device__ __forceinline__ float tanhfast(float x) {
    return 1.0f - 2.0f * __builtin_amdgcn_rcpf(1.0f + __expf(2.0f * x));
}

__device__ __forceinline__ float frame_val(const float* __restrict__ obs,
                                           const float* __restrict__ pred,
                                           int F, int d) {
    return (F < 9) ? obs[F * (NT * 2) + d] : pred[(F - 9) * (NT * 2) + d];
}

// 1024 threads = 16 waves = 4 waves/SIMD. Occupancy is IDENTICAL for any
// VGPR count <= 128 (single block), so holding the f16 W_hh half-row in
// 32 VGPRs is free. Weights round-trip through LDS: ds_read results CANNOT
// be rematerialized across barriers (unlike the global loads the allocator
// kept re-issuing in R2-R5), so they must stay register-resident.
__launch_bounds__(1024, 4)
__global__ void lstm_disc_kernel(const float* __restrict__ observed,
                                 const float* __restrict__ prediction,
                                 const float* __restrict__ W_emb,
                                 const float* __restrict__ b_emb,
                                 const float* __restrict__ W_ih,
                                 const float* __restrict__ W_hh,
                                 const float* __restrict__ b_ih,
                                 const float* __restrict__ b_hh,
                                 const float* __restrict__ W1,
                                 const float* __restrict__ b1,
                                 const float* __restrict__ W2,
                                 const float* __restrict__ b2,
                                 const float* __restrict__ W3,
                                 const float* __restrict__ b3,
                                 float* __restrict__ out)
{
    const int tid  = (int)threadIdx.x;   // 0..1023
    const int lane = tid & 63;
    const int j    = tid & 511;          // gate index
    const int p    = tid >> 9;           // half index (wave-uniform)

    __shared__ uint4    whh4[8 * 1024];  // 131072 B: f16x2 W_hh; granule g at whh4[g*1024+tid]
    __shared__ unsigned xs_pk[21 * 32];  // f16x2 input vectors
    __shared__ float    ppart[1024];     // per-step dot partials
    __shared__ unsigned hpk[64];         // h as f16 pairs
    __shared__ float    hfin[128];       // fp32 h (for MLP tail)
    __shared__ float    velx[21], vely[21], maskf[21];
    __shared__ float    mlp1[64], mlp2[32];

    // ---- (a) velocities + visibility masks for track 0 ----
    if (tid < 20) {
        float ax = frame_val(observed, prediction, tid,     0);
        float ay = frame_val(observed, prediction, tid,     1);
        float bx = frame_val(observed, prediction, tid + 1, 0);
        float by = frame_val(observed, prediction, tid + 1, 1);
        unsigned ua = __float_as_uint(ax) & 0x7fffffffu;
        unsigned ub = __float_as_uint(bx) & 0x7fffffffu;
        bool m = !((ua > 0x7f800000u) || (ub > 0x7f800000u));   // NaN-safe
        maskf[tid + 1] = m ? 1.0f : 0.0f;
        velx[tid + 1]  = m ? (bx - ax) * SCALEF : 0.0f;
        vely[tid + 1]  = m ? (by - ay) * SCALEF : 0.0f;
    }
    if (tid == 20) { maskf[0] = 1.0f; velx[0] = 0.0f; vely[0] = 0.0f; }

    // ---- W_ih half-row -> 16 f16x2 regs (dies after gxr phase) ----
    unsigned xw[16];
    {
        const float4* Wi = reinterpret_cast<const float4*>(W_ih + j * 64 + 32 * p);
        #pragma unroll
        for (int q = 0; q < 8; ++q) {
            float4 w = Wi[q];
            xw[2 * q]     = pk2(w.x, w.y);
            xw[2 * q + 1] = pk2(w.z, w.w);
        }
        #pragma unroll
        for (int q = 0; q < 16; ++q) asm volatile("" : "+v"(xw[q]));
    }
    const float bias = b_ih[j] + b_hh[j];

    __syncthreads();    // velx/maskf ready

    // ---- (b) x vectors, packed f16 ----
    unsigned short* xs16 = (unsigned short*)xs_pk;
    for (int idx = tid; idx < 21 * 64; idx += 1024) {
        int s = idx >> 6, e = idx & 63;
        float v;
        if (s == 0)      v = (e == 62) ? 1.0f : 0.0f;
        else if (e < 62) v = fmaxf(velx[s] * W_emb[2 * e] + vely[s] * W_emb[2 * e + 1] + b_emb[e], 0.0f);
        else             v = 0.0f;
        xs16[s * 64 + e] = __builtin_bit_cast(unsigned short, (_Float16)v);
    }

    // ---- (c) stage W_hh half-row into LDS, lane-contiguous granules ----
    {
        const float4* Wh = reinterpret_cast<const float4*>(W_hh + j * 128 + 64 * p);
        #pragma unroll
        for (int g = 0; g < 8; ++g) {
            float4 wa = Wh[2 * g], wb = Wh[2 * g + 1];
            uint4 u;
            u.x = pk2(wa.x, wa.y); u.y = pk2(wa.z, wa.w);
            u.z = pk2(wb.x, wb.y); u.w = pk2(wb.z, wb.w);
            whh4[g * 1024 + tid] = u;   // wave writes 1024 contiguous B: conflict-free
        }
    }

    unsigned mbits = 0;
    #pragma unroll
    for (int s = 0; s < 21; ++s) mbits |= (maskf[s] != 0.0f ? 1u : 0u) << s;

    __syncthreads();    // xs_pk + whh4 ready

    // ---- (c2) per-thread gx[s] into 21 registers (x-dot off the serial path)
    float gxr[21];
    gxr[0] = (p == 0) ? bias : upk_lo(xw[15]);   // one-hot at e=62 -> W_ih[j][62]
    #pragma unroll
    for (int s = 1; s < 21; ++s) {
        unsigned xp = xs_pk[s * 32 + 16 * p + (lane & 15)];
        float a0 = (p == 0) ? bias : 0.0f, a1 = 0.0f;
        #pragma unroll
        for (int q = 0; q < 16; ++q) {
            if (q & 1) a1 = dot2(xw[q], rlu(xp, q), a1);
            else       a0 = dot2(xw[q], rlu(xp, q), a0);
        }
        gxr[s] = a0 + a1;
    }

    // ---- (c3) hoist W_hh half-row from LDS into 8 uint4 registers (once) ----
    uint4 w0 = whh4[0 * 1024 + tid], w1 = whh4[1 * 1024 + tid];
    uint4 w2 = whh4[2 * 1024 + tid], w3 = whh4[3 * 1024 + tid];
    uint4 w4 = whh4[4 * 1024 + tid], w5 = whh4[5 * 1024 + tid];
    uint4 w6 = whh4[6 * 1024 + tid], w7 = whh4[7 * 1024 + tid];

    // ---- (d) serial recurrence: weights in registers, h broadcast via readlane
    unsigned short* hpk16 = (unsigned short*)hpk;
    float creg = 0.0f;
    unsigned hp = 0u;                    // packed h pair (32p + lane&31)
    #pragma unroll
    for (int s = 0; s < 21; ++s) {
        if (mbits & (1u << s)) {         // uniform branch
            float a0 = gxr[s], a1 = 0.0f;
            a0 = dot2(w0.x, rlu(hp,  0), a0); a1 = dot2(w0.y, rlu(hp,  1), a1);
            a0 = dot2(w0.z, rlu(hp,  2), a0); a1 = dot2(w0.w, rlu(hp,  3), a1);
            a0 = dot2(w1.x, rlu(hp,  4), a0); a1 = dot2(w1.y, rlu(hp,  5), a1);
            a0 = dot2(w1.z, rlu(hp,  6), a0); a1 = dot2(w1.w, rlu(hp,  7), a1);
            a0 = dot2(w2.x, rlu(hp,  8), a0); a1 = dot2(w2.y, rlu(hp,  9), a1);
            a0 = dot2(w2.z, rlu(hp, 10), a0); a1 = dot2(w2.w, rlu(hp, 11), a1);
            a0 = dot2(w3.x, rlu(hp, 12), a0); a1 = dot2(w3.y, rlu(hp, 13), a1);
            a0 = dot2(w3.z, rlu(hp, 14), a0); a1 = dot2(w3.w, rlu(hp, 15), a1);
            a0 = dot2(w4.x, rlu(hp, 16), a0); a1 = dot2(w4.y, rlu(hp, 17), a1);
            a0 = dot2(w4.z, rlu(hp, 18), a0); a1 = dot2(w4.w, rlu(hp, 19), a1);
            a0 = dot2(w5.x, rlu(hp, 20), a0); a1 = dot2(w5.y, rlu(hp, 21), a1);
            a0 = dot2(w5.z, rlu(hp, 22), a0); a1 = dot2(w5.w, rlu(hp, 23), a1);
            a0 = dot2(w6.x, rlu(hp, 24), a0); a1 = dot2(w6.y, rlu(hp, 25), a1);
            a0 = dot2(w6.z, rlu(hp, 26), a0); a1 = dot2(w6.w, rlu(hp, 27), a1);
            a0 = dot2(w7.x, rlu(hp, 28), a0); a1 = dot2(w7.y, rlu(hp, 29), a1);
            a0 = dot2(w7.z, rlu(hp, 30), a0); a1 = dot2(w7.w, rlu(hp, 31), a1);
            ppart[tid] = a0 + a1;
            __syncthreads();
            if (tid < 128) {             // fused activation + cell update
                float gi = sigf(    ppart[tid      ] + ppart[512 + tid]);
                float gf = sigf(    ppart[128 + tid] + ppart[640 + tid]);
                float gg = tanhfast(ppart[256 + tid] + ppart[768 + tid]);
                float go = sigf(    ppart[384 + tid] + ppart[896 + tid]);
                creg = fmaf(gf, creg, gi * gg);
                float hv = go * tanhfast(creg);
                hfin[tid] = hv;
                hpk16[tid] = __builtin_bit_cast(unsigned short, (_Float16)hv);
            }
            __syncthreads();
            hp = hpk[32 * p + (lane & 31)];
        }
    }

    // ---- (e) classifier MLP on h (track 0) ----
    if (tid < 64) {
        const float4* W1r = reinterpret_cast<const float4*>(W1 + tid * 128);
        float a = b1[tid];
        #pragma unroll
        for (int q = 0; q < 32; ++q) {
            float4 w = W1r[q];
            a = fmaf(w.x, hfin[4*q], a);   a = fmaf(w.y, hfin[4*q+1], a);
            a = fmaf(w.z, hfin[4*q+2], a); a = fmaf(w.w, hfin[4*q+3], a);
        }
        mlp1[tid] = fmaxf(a, 0.0f);
    }
    __syncthreads();
    if (tid < 32) {
        const float4* W2r = reinterpret_cast<const float4*>(W2 + tid * 64);
        float a = b2[tid];
        #pragma unroll
        for (int q = 0; q < 16; ++q) {
            float4 w = W2r[q];
            a = fmaf(w.x, mlp1[4*q], a);   a = fmaf(w.y, mlp1[4*q+1], a);
            a = fmaf(w.z, mlp1[4*q+2], a); a = fmaf(w.w, mlp1[4*q+3], a);
        }
        mlp2[tid] = fmaxf(a, 0.0f);
    }
    __syncthreads();
    if (tid == 0) {
        float a = b3[0];
        #pragma unroll
        for (int k = 0; k < 32; ++k) a += W3[k] * mlp2[k];
        out[0] = fmaxf(a, 0.0f);
    }
}

extern "C" void kernel_launch(void* const* d_in, const int* in_sizes, int n_in,
                              void* d_out, int out_size, void* d_ws, size_t ws_size,
                              hipStream_t stream) {
    lstm_disc_kernel<<<1, 1024, 0, stream>>>(
        (const float*)d_in[0],  (const float*)d_in[1],
        (const float*)d_in[2],  (const float*)d_in[3],
        (const float*)d_in[4],  (const float*)d_in[5],
        (const float*)d_in[6],  (const float*)d_in[7],
        (const float*)d_in[8],  (const float*)d_in[9],
        (const float*)d_in[10], (const float*)d_in[11],
        (const float*)d_in[12], (const float*)d_in[13],
        (float*)d_out);
}